// Round 2
// baseline (73.473 us; speedup 1.0000x reference)
//
#include <hip/hip_runtime.h>
#include <math.h>

// S4D diagonal SSM kernel generation (ZOH, real_type='exp', rep=1)
// K[h,l] = sum_n Re( G[h,n] * w[h,n]^l ),  w = exp(dt*A),  G = 2*B*C*(w-1)/A.
//
// Round-5 resubmit (round-1 bench was GPUAcquisitionTimeout; no data):
//  - SAME grid/block/occupancy as round-4: 768 blocks x 256 threads,
//    __launch_bounds__(256,3) -> VGPR cap 170, 3 blocks/CU, zero tail.
//  - n-pairs processed ONE at a time (8 rolled iterations) instead of two
//    fused pairs. Identical instruction count (8x32x3 = 768 pk inner ops,
//    48 LDS param reads, 48 transcendentals), but peak live-register set
//    during the polar init drops from ~145 to ~105: acc2[32] (64 VGPR,
//    live whole kernel) no longer coexists with 8 float4 tiles + 4 seed
//    pairs + 12 trans temps. Theory: the 170 cap was forcing partial
//    scratch spill of acc2 into the fully-unrolled inner loop.
//  - sP1 slimmed float4 -> v2f (zw were zero padding): -512B LDS,
//    ds_read_b64 instead of b128.
//  - recurrence + polar init + 2-stage LDS tree reduction unchanged
//    (validated r2/r3/r4).

typedef float v2f __attribute__((ext_vector_type(2)));

#define H_DIM 768
#define N_DIM 64
#define L_DIM 2048
#define TPB   256
#define LTH   64   // l-threads per h
#define LCH   32   // l per thread

__global__ __launch_bounds__(TPB, 3) void s4d_gen_kernel(
    const float* __restrict__ log_dt,
    const float* __restrict__ B_ri,
    const float* __restrict__ inv_A_real,
    const float* __restrict__ A_imag,
    const float* __restrict__ C_ri,
    float* __restrict__ out)
{
    __shared__ float4 sP0[N_DIM];        // {r32f (revs of w^32 mod 1), l2m32 (log2|w^32|), Gr, Gi}
    __shared__ v2f    sGw[N_DIM];        // {Gwr, Gwi}
    __shared__ v2f    sC1p[N_DIM / 2];   // c1 = 2Re(w), pair-packed
    __shared__ v2f    sNC2p[N_DIM / 2];  // -|w|^2, pair-packed
    __shared__ float  sRed[2][LCH][LTH]; // reduction buffer [grp][j][tl]

    const int h  = blockIdx.x;
    const int t  = threadIdx.x;
    const int nb = t >> 6;   // n-group 0..3 (wave-uniform)
    const int tl = t & 63;   // l-chunk  0..63

    // ---- setup: one thread per n ----
    if (t < N_DIM) {
        const int n   = t;
        const int idx = h * N_DIM + n;
        const float dt = expf(log_dt[h]);
        const float Ar = -expf(inv_A_real[idx]);
        const float Ai = A_imag[idx];
        const float dtAr = Ar * dt;
        const float dtAi = Ai * dt;
        const float e  = expf(dtAr);
        float s, c;
        sincosf(dtAi, &s, &c);
        const float wr = e * c, wi = e * s;
        const float inv = 1.0f / (Ar * Ar + Ai * Ai);
        const float nr = wr - 1.0f, ni = wi;
        const float qr = (nr * Ar + ni * Ai) * inv;
        const float qi = (ni * Ar - nr * Ai) * inv;
        const float Br = B_ri[2 * idx], Bi = B_ri[2 * idx + 1];
        const float Cr = C_ri[2 * idx], Ci = C_ri[2 * idx + 1];
        const float BCr = Br * Cr - Bi * Ci;
        const float BCi = Br * Ci + Bi * Cr;
        const float Gr = 2.0f * (BCr * qr - BCi * qi);
        const float Gi = 2.0f * (BCr * qi + BCi * qr);
        // phase of w^32 in revolutions, reduced mod 1 in double (setup-only)
        const double revs32 = (double)dtAi * (32.0 / (2.0 * M_PI));
        const float  r32f   = (float)(revs32 - floor(revs32));
        // log2 |w^32| = 32 * dtAr * log2(e)
        const float  l2m32  = dtAr * (32.0f * 1.4426950408889634f);
        sP0[n] = make_float4(r32f, l2m32, Gr, Gi);
        sGw[n] = (v2f){Gr * wr - Gi * wi, Gr * wi + Gi * wr};
        ((float*)sC1p)[n]  = 2.0f * wr;
        ((float*)sNC2p)[n] = -(wr * wr + wi * wi);
    }
    __syncthreads();

    v2f acc2[LCH];
    #pragma unroll
    for (int j = 0; j < LCH; ++j) acc2[j] = (v2f){0.0f, 0.0f};

    const int   nbase = nb * 16;
    const float tlf   = (float)tl;

    #pragma unroll 1
    for (int pq = 0; pq < 8; ++pq) {
        const int n0 = nbase + 2 * pq;   // this iteration's pair: (n0, n0+1)

        const float4 p0 = sP0[n0], p1 = sP0[n0 + 1];
        const v2f    q0 = sGw[n0], q1 = sGw[n0 + 1];

        // ---- polar init: u = w^(32 tl); seeds s0 = Re(G u), s1 = Re(G w u) ----
        const float f0 = __builtin_amdgcn_fractf(p0.x * tlf);
        const float f1 = __builtin_amdgcn_fractf(p1.x * tlf);
        const float sn0 = __builtin_amdgcn_sinf(f0), cs0 = __builtin_amdgcn_cosf(f0);
        const float sn1 = __builtin_amdgcn_sinf(f1), cs1 = __builtin_amdgcn_cosf(f1);
        const float m0 = __builtin_amdgcn_exp2f(p0.y * tlf);
        const float m1 = __builtin_amdgcn_exp2f(p1.y * tlf);
        const float ur0 = m0 * cs0, ui0 = m0 * sn0;
        const float ur1 = m1 * cs1, ui1 = m1 * sn1;

        v2f s0 = (v2f){fmaf(p0.z, ur0, -(p0.w * ui0)),
                       fmaf(p1.z, ur1, -(p1.w * ui1))};
        v2f s1 = (v2f){fmaf(q0.x, ur0, -(q0.y * ui0)),
                       fmaf(q1.x, ur1, -(q1.y * ui1))};

        const v2f c1  = sC1p[n0 >> 1];
        const v2f nc2 = sNC2p[n0 >> 1];

        // ---- inner: order-2 real recurrence, pair-packed ----
        #pragma unroll
        for (int j = 0; j < LCH; ++j) {
            acc2[j] += s0;                                   // v_pk_add_f32
            v2f tt = c1 * s1;                                // v_pk_mul_f32
            v2f nx = __builtin_elementwise_fma(nc2, s0, tt); // v_pk_fma_f32
            s0 = s1; s1 = nx;
        }
    }

    // horizontal add: pair -> scalar per j
    float acc[LCH];
    #pragma unroll
    for (int j = 0; j < LCH; ++j) acc[j] = acc2[j].x + acc2[j].y;

    // ---- 2-stage tree reduction over the 4 n-groups ----
    if (nb >= 2) {
        #pragma unroll
        for (int j = 0; j < LCH; ++j) sRed[nb - 2][j][tl] = acc[j];
    }
    __syncthreads();
    if (nb < 2) {
        #pragma unroll
        for (int j = 0; j < LCH; ++j) acc[j] += sRed[nb][j][tl];
    }
    __syncthreads();
    if (nb == 1) {
        #pragma unroll
        for (int j = 0; j < LCH; ++j) sRed[0][j][tl] = acc[j];
    }
    __syncthreads();
    if (nb == 0) {
        #pragma unroll
        for (int j = 0; j < LCH; ++j) acc[j] += sRed[0][j][tl];
        float* op = out + (size_t)h * L_DIM + tl * LCH;
        #pragma unroll
        for (int j = 0; j < LCH; j += 4) {
            *reinterpret_cast<float4*>(op + j) =
                make_float4(acc[j], acc[j + 1], acc[j + 2], acc[j + 3]);
        }
    }
}

extern "C" void kernel_launch(void* const* d_in, const int* in_sizes, int n_in,
                              void* d_out, int out_size, void* d_ws, size_t ws_size,
                              hipStream_t stream) {
    const float* log_dt     = (const float*)d_in[0];
    const float* B_ri       = (const float*)d_in[1];
    const float* inv_A_real = (const float*)d_in[2];
    const float* A_imag     = (const float*)d_in[3];
    const float* C_ri       = (const float*)d_in[4];
    float* out = (float*)d_out;
    hipLaunchKernelGGL(s4d_gen_kernel, dim3(H_DIM), dim3(TPB), 0, stream,
                       log_dt, B_ri, inv_A_real, A_imag, C_ri, out);
}